// Round 3
// baseline (196.042 us; speedup 1.0000x reference)
//
#include <hip/hip_runtime.h>
#include <hip/hip_bf16.h>

#define BN_EPS 1e-5f
#define MG 2                 // 16-edge tiles per group
#define GEDGES 32            // edges per group

typedef short bf16x8 __attribute__((ext_vector_type(8)));
typedef float f32x4  __attribute__((ext_vector_type(4)));

static __device__ __forceinline__ unsigned short f2bf(float f) {
    union { float f; unsigned int u; } v; v.f = f;
    unsigned int u = v.u;
    unsigned int r = (u + 0x7FFFu + ((u >> 16) & 1u)) >> 16;   // RNE
    return (unsigned short)r;
}

static __device__ __forceinline__ unsigned short f2bf_hw(float f) {
    __hip_bfloat16 b = __float2bfloat16(f);
    union { __hip_bfloat16 b; unsigned short u; } v; v.b = b;
    return v.u;
}

// ---------------- fused prep kernel (unchanged) ----------------
__global__ __launch_bounds__(256) void k_prep(
        const float* __restrict__ h, unsigned short* __restrict__ hb, int n4, int nCvt,
        const float* __restrict__ W0, const float* __restrict__ b0,
        const float* __restrict__ W1, const float* __restrict__ b1,
        const float* __restrict__ W2, const float* __restrict__ b2,
        const float* __restrict__ g0, const float* __restrict__ be0,
        const float* __restrict__ m0, const float* __restrict__ v0,
        const float* __restrict__ g1, const float* __restrict__ be1,
        const float* __restrict__ m1, const float* __restrict__ v1,
        const float* __restrict__ g2, const float* __restrict__ be2,
        const float* __restrict__ m2, const float* __restrict__ v2,
        unsigned short* __restrict__ W0sw, unsigned short* __restrict__ W1sw,
        float* __restrict__ b0f, float* __restrict__ b1f,
        float* __restrict__ w2f, float* __restrict__ b2f) {
    const int b = blockIdx.x;
    const int tid = threadIdx.x;

    if (b < nCvt) {                       // ---- h -> bf16 ----
        int i = b * 256 + tid;
        if (i < n4) {
            float4 f = ((const float4*)h)[i];
            ushort4 o;
            o.x = f2bf(f.x); o.y = f2bf(f.y); o.z = f2bf(f.z); o.w = f2bf(f.w);
            ((ushort4*)hb)[i] = o;
        }
        return;
    }
    int br = b - nCvt;
    if (br < 128) {                        // ---- W0sw ----
        int t = br * 256 + tid;
        int j = t & 7, lane = (t >> 3) & 63, nt = (t >> 9) & 7, kb = t >> 12;
        int k = kb * 32 + (lane >> 4) * 8 + j;
        int n = nt * 16 + (lane & 15);
        float s = g0[k] * rsqrtf(v0[k] + BN_EPS);
        W0sw[t] = f2bf(W0[n * 256 + k] * s);
        return;
    }
    br -= 128;
    if (br < 64) {                         // ---- W1sw ----
        int t = br * 256 + tid;
        int j = t & 7, lane = (t >> 3) & 63, nt = (t >> 9) & 7, kb = t >> 12;
        int k = kb * 32 + (lane >> 4) * 8 + j;
        int n = nt * 16 + (lane & 15);
        float s = g1[k] * rsqrtf(v1[k] + BN_EPS);
        W1sw[t] = f2bf(W1[n * 128 + k] * s);
        return;
    }
    br -= 64;
    {                                      // ---- folded biases (row = br) ----
        if (tid >= 64) return;
        const int i = br, lane = tid;
        float s0 = 0.f;
#pragma unroll
        for (int c = 0; c < 4; c++) {
            int k = c * 64 + lane;
            float sc = g0[k] * rsqrtf(v0[k] + BN_EPS);
            s0 += W0[i * 256 + k] * (be0[k] - m0[k] * sc);
        }
        float s1 = 0.f;
#pragma unroll
        for (int c = 0; c < 2; c++) {
            int k = c * 64 + lane;
            float sc = g1[k] * rsqrtf(v1[k] + BN_EPS);
            s1 += W1[i * 128 + k] * (be1[k] - m1[k] * sc);
        }
        float s2 = 0.f;
        if (i == 0) {
#pragma unroll
            for (int c = 0; c < 2; c++) {
                int k = c * 64 + lane;
                float sc = g2[k] * rsqrtf(v2[k] + BN_EPS);
                s2 += W2[k] * (be2[k] - m2[k] * sc);
            }
        }
#pragma unroll
        for (int off = 1; off < 64; off <<= 1) {
            s0 += __shfl_xor(s0, off);
            s1 += __shfl_xor(s1, off);
            s2 += __shfl_xor(s2, off);
        }
        if (lane == 0) {
            b0f[i] = b0[i] + s0;
            b1f[i] = b1[i] + s1;
            w2f[i] = W2[i] * (g2[i] * rsqrtf(v2[i] + BN_EPS));
            if (i == 0) b2f[0] = b2[0] + s2;
        }
    }
}

// ---------------- main kernel: direct-to-register A gather, 3 blocks/CU ----------------
// R2 post-mortem: R0 was ALREADY at 3 blocks/CU (84 VGPR + ~80 AGPR = 164 <= 170);
// (256,2) DROPPED residency to 2 (occupancy 25->18.4%). New theory: the shared DS pipe
// is the limiter — per block-iter ~120 KB LDS traffic (4 waves x full-Abuf re-read +
// stage1 + DMA + x1S) = ~960 cyc; x3 blocks = ~2880 cyc ~= the observed 3120 cyc/group,
// while MFMA needs only 932. Fix: A-fragments are per-lane gatherable (lane l <- row
// e[l&15], 16B at quad offset == exactly the DMA's global addresses), so load A straight
// into VGPRs with global_load_dwordx4 (hb is 2.56 MB, L2-resident). Kills Abuf + DMA +
// 96 KB/iter of DS traffic. Row indices prefetched 1 group ahead (4 rows/lane). B1 moves
// to per-iter loads from W1sw (same 32 KB addresses every iter -> L1-hot) to keep the
// combined reg count under the 170 cap for 3 waves/SIMD.
__global__ __launch_bounds__(256, 3) void k_main(
        const int* __restrict__ src, const int* __restrict__ dst,
        const unsigned short* __restrict__ hb,
        const unsigned short* __restrict__ W0sw, const unsigned short* __restrict__ W1sw,
        const float* __restrict__ b0f, const float* __restrict__ b1f,
        const float* __restrict__ w2f, const float* __restrict__ b2fp,
        float* __restrict__ out, int E, int nGroups) {
    __shared__ __align__(16) unsigned short x1S[2][MG][4][64][8];         // 2 x 8 KB
    __shared__ float pS[2][4][GEDGES];                                    // 1 KB

    const int tid  = threadIdx.x;
    const int wave = tid >> 6;
    const int lane = tid & 63;
    const int quad = lane >> 4;
    const int m    = lane & 15;

    // ---- persistent weight fragments: B0 only (64 regs). B1 is loaded per-iter. ----
    bf16x8 B0[8][2];
#pragma unroll
    for (int kb = 0; kb < 8; kb++)
#pragma unroll
        for (int hh = 0; hh < 2; hh++)
            B0[kb][hh] = *(const bf16x8*)(W0sw + ((kb * 8 + (wave * 2 + hh)) * 64 + lane) * 8);

    float b0v[2], b1v[2], w2v[2];
#pragma unroll
    for (int hh = 0; hh < 2; hh++) {
        int n = (wave * 2 + hh) * 16 + m;
        b0v[hh] = b0f[n];
        b1v[hh] = b1f[n];
        w2v[hh] = w2f[n];
    }
    const float b2s = *b2fp;
    const int stride = gridDim.x;

    int gi = blockIdx.x;
    int p = 0;
    int eM1 = -1, eM2 = -1;     // eBase of groups t-1, t-2
    int rs[MG], rd[MG];         // this lane's src/dst rows for G_t   (edge g*16 + m)
    int rsN[MG], rdN[MG];       // prefetched rows for G_{t+1}

    // ---- prologue: load row indices for G_first ----
    {
        int eb = gi * GEDGES;
#pragma unroll
        for (int g = 0; g < MG; g++) {
            int e = eb + g * 16 + m; if (e >= E) e = E - 1;
            rs[g] = src[e];
            rd[g] = dst[e];
        }
    }

    for (; gi < nGroups; gi += stride, p ^= 1) {
        __syncthreads();   // x1S[p^1]/pS[p^1] (written at t-1) visible to all waves

        // ---- issue A-loads for G_t straight into registers (16 x global_load_dwordx4,
        //      L2-hit ~200-300 cyc; consumption below + 3-block TLP hides it) ----
        bf16x8 a0s[4][MG], a0d[4][MG];
#pragma unroll
        for (int kb4 = 0; kb4 < 4; kb4++)
#pragma unroll
            for (int g = 0; g < MG; g++) {
                a0s[kb4][g] = *(const bf16x8*)(hb + (size_t)rs[g] * 128 + kb4 * 32 + quad * 8);
                a0d[kb4][g] = *(const bf16x8*)(hb + (size_t)rd[g] * 128 + kb4 * 32 + quad * 8);
            }

        // ---- store out(G_{t-2}) from pS[p^1] ----
        if (eM2 >= 0 && wave == 0 && lane < GEDGES) {
            int e = eM2 + lane;
            if (e < E)
                out[e] = pS[p ^ 1][0][lane] + pS[p ^ 1][1][lane] +
                         pS[p ^ 1][2][lane] + pS[p ^ 1][3][lane] + b2s;
        }

        // ---- prefetch row indices for G_{t+1} ----
        {
            int gN = gi + stride;
            int ebN = (gN < nGroups ? gN : gi) * GEDGES;
#pragma unroll
            for (int g = 0; g < MG; g++) {
                int e = ebN + g * 16 + m; if (e >= E) e = E - 1;
                rsN[g] = src[e];
                rdN[g] = dst[e];
            }
        }

        // ---- stage 0 (G_t): a0 regs -> acc0 -> x1S[p] ----
        {
            f32x4 acc0[MG][2];
#pragma unroll
            for (int g = 0; g < MG; g++)
#pragma unroll
                for (int hh = 0; hh < 2; hh++) acc0[g][hh] = (f32x4){0.f, 0.f, 0.f, 0.f};

#pragma unroll
            for (int kb4 = 0; kb4 < 4; kb4++)
#pragma unroll
                for (int hh = 0; hh < 2; hh++)
#pragma unroll
                    for (int g = 0; g < MG; g++)
                        acc0[g][hh] = __builtin_amdgcn_mfma_f32_16x16x32_bf16(a0s[kb4][g], B0[kb4][hh], acc0[g][hh], 0, 0, 0);
#pragma unroll
            for (int kb4 = 0; kb4 < 4; kb4++)
#pragma unroll
                for (int hh = 0; hh < 2; hh++)
#pragma unroll
                    for (int g = 0; g < MG; g++)
                        acc0[g][hh] = __builtin_amdgcn_mfma_f32_16x16x32_bf16(a0d[kb4][g], B0[4 + kb4][hh], acc0[g][hh], 0, 0, 0);

#pragma unroll
            for (int g = 0; g < MG; g++) {
#pragma unroll
                for (int hh = 0; hh < 2; hh++) {
                    int qp = (hh << 1) | (m >> 3);
                    int j  = m & 7;
#pragma unroll
                    for (int r = 0; r < 4; r++) {
                        float v = acc0[g][hh][r] + b0v[hh];
                        v = v > 0.f ? v : 0.f;
                        x1S[p][g][wave][qp * 16 + quad * 4 + r][j] = f2bf_hw(v);
                    }
                }
            }
        }

        // ---- stage 1+2 (G_{t-1}): x1S[p^1] -> acc1 -> partials -> pS[p] ----
        if (eM1 >= 0) {
            bf16x8 B1[4][2];
#pragma unroll
            for (int kb = 0; kb < 4; kb++)
#pragma unroll
                for (int hh = 0; hh < 2; hh++)
                    B1[kb][hh] = *(const bf16x8*)(W1sw + ((kb * 8 + (wave * 2 + hh)) * 64 + lane) * 8);

            f32x4 acc1[MG][2];
#pragma unroll
            for (int g = 0; g < MG; g++)
#pragma unroll
                for (int hh = 0; hh < 2; hh++) acc1[g][hh] = (f32x4){0.f, 0.f, 0.f, 0.f};

#pragma unroll
            for (int kb = 0; kb < 4; kb++) {
                bf16x8 a1[MG];
#pragma unroll
                for (int g = 0; g < MG; g++)
                    a1[g] = *(const bf16x8*)&x1S[p ^ 1][g][kb][lane][0];
#pragma unroll
                for (int hh = 0; hh < 2; hh++)
#pragma unroll
                    for (int g = 0; g < MG; g++)
                        acc1[g][hh] = __builtin_amdgcn_mfma_f32_16x16x32_bf16(a1[g], B1[kb][hh], acc1[g][hh], 0, 0, 0);
            }

#pragma unroll
            for (int g = 0; g < MG; g++) {
                float s[4] = {0.f, 0.f, 0.f, 0.f};
#pragma unroll
                for (int hh = 0; hh < 2; hh++)
#pragma unroll
                    for (int r = 0; r < 4; r++) {
                        float v = acc1[g][hh][r] + b1v[hh];
                        v = v > 0.f ? v : 0.f;
                        s[r] += v * w2v[hh];
                    }
#pragma unroll
                for (int off = 1; off < 16; off <<= 1)
#pragma unroll
                    for (int r = 0; r < 4; r++) s[r] += __shfl_xor(s[r], off, 16);
                if (m == 0) {
#pragma unroll
                    for (int r = 0; r < 4; r++)
                        pS[p][wave][g * 16 + quad * 4 + r] = s[r];
                }
            }
        }

        eM2 = eM1;
        eM1 = gi * GEDGES;
#pragma unroll
        for (int g = 0; g < MG; g++) { rs[g] = rsN[g]; rd[g] = rdN[g]; }
    }

    // ---- drain: store(G_{L-1}); stage1+2(G_L); store(G_L) ----
    __syncthreads();
    if (eM2 >= 0 && wave == 0 && lane < GEDGES) {
        int e = eM2 + lane;
        if (e < E)
            out[e] = pS[p ^ 1][0][lane] + pS[p ^ 1][1][lane] +
                     pS[p ^ 1][2][lane] + pS[p ^ 1][3][lane] + b2s;
    }
    if (eM1 >= 0) {
        bf16x8 B1[4][2];
#pragma unroll
        for (int kb = 0; kb < 4; kb++)
#pragma unroll
            for (int hh = 0; hh < 2; hh++)
                B1[kb][hh] = *(const bf16x8*)(W1sw + ((kb * 8 + (wave * 2 + hh)) * 64 + lane) * 8);

        f32x4 acc1[MG][2];
#pragma unroll
        for (int g = 0; g < MG; g++)
#pragma unroll
            for (int hh = 0; hh < 2; hh++) acc1[g][hh] = (f32x4){0.f, 0.f, 0.f, 0.f};
#pragma unroll
        for (int kb = 0; kb < 4; kb++) {
            bf16x8 a1[MG];
#pragma unroll
            for (int g = 0; g < MG; g++)
                a1[g] = *(const bf16x8*)&x1S[p ^ 1][g][kb][lane][0];
#pragma unroll
            for (int hh = 0; hh < 2; hh++)
#pragma unroll
                for (int g = 0; g < MG; g++)
                    acc1[g][hh] = __builtin_amdgcn_mfma_f32_16x16x32_bf16(a1[g], B1[kb][hh], acc1[g][hh], 0, 0, 0);
        }
#pragma unroll
        for (int g = 0; g < MG; g++) {
            float s[4] = {0.f, 0.f, 0.f, 0.f};
#pragma unroll
            for (int hh = 0; hh < 2; hh++)
#pragma unroll
                for (int r = 0; r < 4; r++) {
                    float v = acc1[g][hh][r] + b1v[hh];
                    v = v > 0.f ? v : 0.f;
                    s[r] += v * w2v[hh];
                }
#pragma unroll
            for (int off = 1; off < 16; off <<= 1)
#pragma unroll
                for (int r = 0; r < 4; r++) s[r] += __shfl_xor(s[r], off, 16);
            if (m == 0) {
#pragma unroll
                for (int r = 0; r < 4; r++)
                    pS[p][wave][g * 16 + quad * 4 + r] = s[r];
            }
        }
    }
    __syncthreads();
    if (eM1 >= 0 && wave == 0 && lane < GEDGES) {
        int e = eM1 + lane;
        if (e < E)
            out[e] = pS[p][0][lane] + pS[p][1][lane] +
                     pS[p][2][lane] + pS[p][3][lane] + b2s;
    }
}

// ---------------- launcher ----------------
extern "C" void kernel_launch(void* const* d_in, const int* in_sizes, int n_in,
                              void* d_out, int out_size, void* d_ws, size_t ws_size,
                              hipStream_t stream) {
    const float* h   = (const float*)d_in[0];
    const int*   src = (const int*)d_in[1];
    const int*   dst = (const int*)d_in[2];
    const float* W0  = (const float*)d_in[3];
    const float* b0  = (const float*)d_in[4];
    const float* W1  = (const float*)d_in[5];
    const float* b1  = (const float*)d_in[6];
    const float* W2  = (const float*)d_in[7];
    const float* b2  = (const float*)d_in[8];
    const float* g0  = (const float*)d_in[9];
    const float* be0 = (const float*)d_in[10];
    const float* g1  = (const float*)d_in[11];
    const float* be1 = (const float*)d_in[12];
    const float* g2  = (const float*)d_in[13];
    const float* be2 = (const float*)d_in[14];
    const float* m0  = (const float*)d_in[15];
    const float* v0  = (const float*)d_in[16];
    const float* m1  = (const float*)d_in[17];
    const float* v1  = (const float*)d_in[18];
    const float* m2  = (const float*)d_in[19];
    const float* v2  = (const float*)d_in[20];
    float* out = (float*)d_out;

    const int hsz = in_sizes[0];          // N*128
    const int E   = in_sizes[1];

    char* ws = (char*)d_ws;
    size_t off = (size_t)hsz * 2;         // hb bytes
    off = (off + 255) & ~(size_t)255;
    unsigned short* hb   = (unsigned short*)ws;
    unsigned short* W0sw = (unsigned short*)(ws + off);  off += 65536;
    unsigned short* W1sw = (unsigned short*)(ws + off);  off += 32768;
    float* b0f = (float*)(ws + off);  off += 512;
    float* b1f = (float*)(ws + off);  off += 512;
    float* w2f = (float*)(ws + off);  off += 512;
    float* b2f = (float*)(ws + off);  off += 16;

    int n4   = hsz / 4;
    int nCvt = (n4 + 255) / 256;
    int prepBlocks = nCvt + 128 + 64 + 128;
    k_prep<<<prepBlocks, 256, 0, stream>>>(h, hb, n4, nCvt,
                                           W0, b0, W1, b1, W2, b2,
                                           g0, be0, m0, v0, g1, be1, m1, v1,
                                           g2, be2, m2, v2,
                                           W0sw, W1sw, b0f, b1f, w2f, b2f);

    int nGroups = (E + GEDGES - 1) / GEDGES;
    int nBlocks = nGroups < 768 ? nGroups : 768;   // 3 blocks/CU (LDS 17.4 KB, combined regs target <=170)
    k_main<<<nBlocks, 256, 0, stream>>>(src, dst, hb, W0sw, W1sw,
                                        b0f, b1f, w2f, b2f, out, E, nGroups);
}

// Round 6
// 141.514 us; speedup vs baseline: 1.3853x; 1.3853x over previous
//
#include <hip/hip_runtime.h>
#include <hip/hip_bf16.h>

#define BN_EPS 1e-5f
#define MG 2                 // 16-edge tiles per group
#define GEDGES 32            // edges per group

typedef short bf16x8 __attribute__((ext_vector_type(8)));   // also generic short8
typedef float f32x4  __attribute__((ext_vector_type(4)));

static __device__ __forceinline__ unsigned short f2bf(float f) {
    union { float f; unsigned int u; } v; v.f = f;
    unsigned int u = v.u;
    unsigned int r = (u + 0x7FFFu + ((u >> 16) & 1u)) >> 16;   // RNE
    return (unsigned short)r;
}

static __device__ __forceinline__ unsigned short f2bf_hw(float f) {
    __hip_bfloat16 b = __float2bfloat16(f);
    union { __hip_bfloat16 b; unsigned short u; } v; v.b = b;
    return v.u;
}

static __device__ __forceinline__ unsigned short f2h(float f) {   // f32 -> f16 bits (RNE)
    union { _Float16 h; unsigned short u; } v; v.h = (_Float16)f;
    return v.u;
}

static __device__ __forceinline__ float h2f(short s) {            // f16 bits -> f32
    union { short s; _Float16 h; } v; v.s = s;
    return (float)v.h;
}

// ---------------- unified prep kernel (R0 form; nCvt=0 skips the h->bf16 pass) ----------------
__global__ __launch_bounds__(256) void k_prep(
        const float* __restrict__ h, unsigned short* __restrict__ hb, int n4, int nCvt,
        const float* __restrict__ W0, const float* __restrict__ b0,
        const float* __restrict__ W1, const float* __restrict__ b1,
        const float* __restrict__ W2, const float* __restrict__ b2,
        const float* __restrict__ g0, const float* __restrict__ be0,
        const float* __restrict__ m0, const float* __restrict__ v0,
        const float* __restrict__ g1, const float* __restrict__ be1,
        const float* __restrict__ m1, const float* __restrict__ v1,
        const float* __restrict__ g2, const float* __restrict__ be2,
        const float* __restrict__ m2, const float* __restrict__ v2,
        unsigned short* __restrict__ W0sw, unsigned short* __restrict__ W1sw,
        float* __restrict__ b0f, float* __restrict__ b1f,
        float* __restrict__ w2f, float* __restrict__ b2f) {
    const int b = blockIdx.x;
    const int tid = threadIdx.x;

    if (b < nCvt) {                       // ---- h -> bf16 ----
        int i = b * 256 + tid;
        if (i < n4) {
            float4 f = ((const float4*)h)[i];
            ushort4 o;
            o.x = f2bf(f.x); o.y = f2bf(f.y); o.z = f2bf(f.z); o.w = f2bf(f.w);
            ((ushort4*)hb)[i] = o;
        }
        return;
    }
    int br = b - nCvt;
    if (br < 128) {                        // ---- W0sw (BN0 scale folded) ----
        int t = br * 256 + tid;
        int j = t & 7, lane = (t >> 3) & 63, nt = (t >> 9) & 7, kb = t >> 12;
        int k = kb * 32 + (lane >> 4) * 8 + j;
        int n = nt * 16 + (lane & 15);
        float s = g0[k] * rsqrtf(v0[k] + BN_EPS);
        W0sw[t] = f2bf(W0[n * 256 + k] * s);
        return;
    }
    br -= 128;
    if (br < 64) {                         // ---- W1sw ----
        int t = br * 256 + tid;
        int j = t & 7, lane = (t >> 3) & 63, nt = (t >> 9) & 7, kb = t >> 12;
        int k = kb * 32 + (lane >> 4) * 8 + j;
        int n = nt * 16 + (lane & 15);
        float s = g1[k] * rsqrtf(v1[k] + BN_EPS);
        W1sw[t] = f2bf(W1[n * 128 + k] * s);
        return;
    }
    br -= 64;
    {                                      // ---- folded biases (row = br, 0..127) ----
        if (tid >= 64) return;
        const int i = br, lane = tid;
        float s0 = 0.f;
#pragma unroll
        for (int c = 0; c < 4; c++) {
            int k = c * 64 + lane;
            float sc = g0[k] * rsqrtf(v0[k] + BN_EPS);
            s0 += W0[i * 256 + k] * (be0[k] - m0[k] * sc);
        }
        float s1 = 0.f;
#pragma unroll
        for (int c = 0; c < 2; c++) {
            int k = c * 64 + lane;
            float sc = g1[k] * rsqrtf(v1[k] + BN_EPS);
            s1 += W1[i * 128 + k] * (be1[k] - m1[k] * sc);
        }
        float s2 = 0.f;
        if (i == 0) {
#pragma unroll
            for (int c = 0; c < 2; c++) {
                int k = c * 64 + lane;
                float sc = g2[k] * rsqrtf(v2[k] + BN_EPS);
                s2 += W2[k] * (be2[k] - m2[k] * sc);
            }
        }
#pragma unroll
        for (int off = 1; off < 64; off <<= 1) {
            s0 += __shfl_xor(s0, off);
            s1 += __shfl_xor(s1, off);
            s2 += __shfl_xor(s2, off);
        }
        if (lane == 0) {
            b0f[i] = b0[i] + s0;
            b1f[i] = b1[i] + s1;
            w2f[i] = W2[i] * (g2[i] * rsqrtf(v2[i] + BN_EPS));
            if (i == 0) b2f[0] = b2[0] + s2;
        }
    }
}

// ======================= PATH A: factorized node projection =======================
// UV[n][0..127] = f16(h[n]@W0s^T + b0f); UV[n][128..255] = f16(h[n]@W0d^T).
__global__ __launch_bounds__(256) void k_node(
        const float* __restrict__ h,
        const unsigned short* __restrict__ W0sw,
        const float* __restrict__ b0f,
        unsigned short* __restrict__ UV, int N) {
    const int tid  = threadIdx.x;
    const int wave = tid >> 6;
    const int lane = tid & 63;
    const int quad = lane >> 4;
    const int m    = lane & 15;
    const int nb   = blockIdx.x * 32;

    bf16x8 B0[8][2];
#pragma unroll
    for (int kb = 0; kb < 8; kb++)
#pragma unroll
        for (int hh = 0; hh < 2; hh++)
            B0[kb][hh] = *(const bf16x8*)(W0sw + ((kb * 8 + (wave * 2 + hh)) * 64 + lane) * 8);

    float b0v[2];
#pragma unroll
    for (int hh = 0; hh < 2; hh++) b0v[hh] = b0f[(wave * 2 + hh) * 16 + m];

    f32x4 au[MG][2], av[MG][2];
#pragma unroll
    for (int g = 0; g < MG; g++)
#pragma unroll
        for (int hh = 0; hh < 2; hh++) {
            au[g][hh] = (f32x4){0.f, 0.f, 0.f, 0.f};
            av[g][hh] = (f32x4){0.f, 0.f, 0.f, 0.f};
        }

#pragma unroll
    for (int g = 0; g < MG; g++) {
        int nrow = nb + g * 16 + m; if (nrow >= N) nrow = N - 1;
        const float* hrow = h + (size_t)nrow * 128;
#pragma unroll
        for (int kb = 0; kb < 4; kb++) {
            const float* hp = hrow + kb * 32 + quad * 8;
            f32x4 f0 = *(const f32x4*)hp;
            f32x4 f1 = *(const f32x4*)(hp + 4);
            bf16x8 a;
            a[0] = (short)f2bf_hw(f0[0]); a[1] = (short)f2bf_hw(f0[1]);
            a[2] = (short)f2bf_hw(f0[2]); a[3] = (short)f2bf_hw(f0[3]);
            a[4] = (short)f2bf_hw(f1[0]); a[5] = (short)f2bf_hw(f1[1]);
            a[6] = (short)f2bf_hw(f1[2]); a[7] = (short)f2bf_hw(f1[3]);
#pragma unroll
            for (int hh = 0; hh < 2; hh++) {
                au[g][hh] = __builtin_amdgcn_mfma_f32_16x16x32_bf16(a, B0[kb][hh],     au[g][hh], 0, 0, 0);
                av[g][hh] = __builtin_amdgcn_mfma_f32_16x16x32_bf16(a, B0[kb + 4][hh], av[g][hh], 0, 0, 0);
            }
        }
    }

#pragma unroll
    for (int g = 0; g < MG; g++)
#pragma unroll
        for (int hh = 0; hh < 2; hh++) {
            int col = (wave * 2 + hh) * 16 + m;
#pragma unroll
            for (int r = 0; r < 4; r++) {
                int node = nb + g * 16 + quad * 4 + r;
                if (node < N) {
                    UV[(size_t)node * 256 + col]       = f2h(au[g][hh][r] + b0v[hh]);
                    UV[(size_t)node * 256 + 128 + col] = f2h(av[g][hh][r]);
                }
            }
        }
}

__global__ __launch_bounds__(256, 3) void k_main_uv(
        const int* __restrict__ src, const int* __restrict__ dst,
        const unsigned short* __restrict__ UV,
        const unsigned short* __restrict__ W1sw,
        const float* __restrict__ b1f, const float* __restrict__ w2f,
        const float* __restrict__ b2fp,
        float* __restrict__ out, int E, int nGroups) {
    __shared__ __align__(16) unsigned short x1S[2][MG][4][64][8];         // 2 x 8 KB
    __shared__ float pS[2][4][GEDGES];                                    // 1 KB

    const int tid  = threadIdx.x;
    const int wave = tid >> 6;
    const int lane = tid & 63;
    const int quad = lane >> 4;
    const int m    = lane & 15;
    const int es   = tid >> 3;
    const int fc   = tid & 7;

    bf16x8 B1[4][2];
#pragma unroll
    for (int kb = 0; kb < 4; kb++)
#pragma unroll
        for (int hh = 0; hh < 2; hh++)
            B1[kb][hh] = *(const bf16x8*)(W1sw + ((kb * 8 + (wave * 2 + hh)) * 64 + lane) * 8);

    float b1v[2], w2v[2];
#pragma unroll
    for (int hh = 0; hh < 2; hh++) {
        int n = (wave * 2 + hh) * 16 + m;
        b1v[hh] = b1f[n];
        w2v[hh] = w2f[n];
    }
    const float b2s = *b2fp;
    const int stride = gridDim.x;

    int gi = blockIdx.x;
    int p = 0;
    int eM1 = -1, eM2 = -1;
    bf16x8 uA, uB, vA, vB;

    {
        int e = gi * GEDGES + es; if (e >= E) e = E - 1;
        int rs_ = src[e], rd_ = dst[e];
        const bf16x8* up = (const bf16x8*)(UV + (size_t)rs_ * 256 + fc * 16);
        const bf16x8* vp = (const bf16x8*)(UV + (size_t)rd_ * 256 + 128 + fc * 16);
        uA = up[0]; uB = up[1]; vA = vp[0]; vB = vp[1];
    }

    for (; gi < nGroups; gi += stride, p ^= 1) {
        __syncthreads();

        if (eM2 >= 0 && wave == 0 && lane < GEDGES) {
            int e = eM2 + lane;
            if (e < E)
                out[e] = pS[p ^ 1][0][lane] + pS[p ^ 1][1][lane] +
                         pS[p ^ 1][2][lane] + pS[p ^ 1][3][lane] + b2s;
        }

        {
            bf16x8 w0, w1;
#pragma unroll
            for (int j = 0; j < 8; j++) {
                float s0 = h2f(uA[j]) + h2f(vA[j]);
                float s1 = h2f(uB[j]) + h2f(vB[j]);
                s0 = s0 > 0.f ? s0 : 0.f;
                s1 = s1 > 0.f ? s1 : 0.f;
                w0[j] = (short)f2bf_hw(s0);
                w1[j] = (short)f2bf_hw(s1);
            }
            int g = es >> 4, s15 = es & 15, kb = fc >> 1, q0 = (fc & 1) * 2;
            *(bf16x8*)&x1S[p][g][kb][q0 * 16 + s15][0]       = w0;
            *(bf16x8*)&x1S[p][g][kb][(q0 + 1) * 16 + s15][0] = w1;
        }

        {
            int gN = gi + stride;
            int ebN = (gN < nGroups ? gN : gi) * GEDGES;
            int e = ebN + es; if (e >= E) e = E - 1;
            int rs_ = src[e], rd_ = dst[e];
            const bf16x8* up = (const bf16x8*)(UV + (size_t)rs_ * 256 + fc * 16);
            const bf16x8* vp = (const bf16x8*)(UV + (size_t)rd_ * 256 + 128 + fc * 16);
            uA = up[0]; uB = up[1]; vA = vp[0]; vB = vp[1];
        }

        if (eM1 >= 0) {
            f32x4 acc1[MG][2];
#pragma unroll
            for (int g = 0; g < MG; g++)
#pragma unroll
                for (int hh = 0; hh < 2; hh++) acc1[g][hh] = (f32x4){0.f, 0.f, 0.f, 0.f};

#pragma unroll
            for (int kb = 0; kb < 4; kb++) {
                bf16x8 a1[MG];
#pragma unroll
                for (int g = 0; g < MG; g++)
                    a1[g] = *(const bf16x8*)&x1S[p ^ 1][g][kb][lane][0];
#pragma unroll
                for (int hh = 0; hh < 2; hh++)
#pragma unroll
                    for (int g = 0; g < MG; g++)
                        acc1[g][hh] = __builtin_amdgcn_mfma_f32_16x16x32_bf16(a1[g], B1[kb][hh], acc1[g][hh], 0, 0, 0);
            }

#pragma unroll
            for (int g = 0; g < MG; g++) {
                float s[4] = {0.f, 0.f, 0.f, 0.f};
#pragma unroll
                for (int hh = 0; hh < 2; hh++)
#pragma unroll
                    for (int r = 0; r < 4; r++) {
                        float v = acc1[g][hh][r] + b1v[hh];
                        v = v > 0.f ? v : 0.f;
                        s[r] += v * w2v[hh];
                    }
#pragma unroll
                for (int off = 1; off < 16; off <<= 1)
#pragma unroll
                    for (int r = 0; r < 4; r++) s[r] += __shfl_xor(s[r], off, 16);
                if (m == 0) {
#pragma unroll
                    for (int r = 0; r < 4; r++)
                        pS[p][wave][g * 16 + quad * 4 + r] = s[r];
                }
            }
        }

        eM2 = eM1;
        eM1 = gi * GEDGES;
    }

    __syncthreads();
    if (eM2 >= 0 && wave == 0 && lane < GEDGES) {
        int e = eM2 + lane;
        if (e < E)
            out[e] = pS[p ^ 1][0][lane] + pS[p ^ 1][1][lane] +
                     pS[p ^ 1][2][lane] + pS[p ^ 1][3][lane] + b2s;
    }
    if (eM1 >= 0) {
        f32x4 acc1[MG][2];
#pragma unroll
        for (int g = 0; g < MG; g++)
#pragma unroll
            for (int hh = 0; hh < 2; hh++) acc1[g][hh] = (f32x4){0.f, 0.f, 0.f, 0.f};
#pragma unroll
        for (int kb = 0; kb < 4; kb++) {
            bf16x8 a1[MG];
#pragma unroll
            for (int g = 0; g < MG; g++)
                a1[g] = *(const bf16x8*)&x1S[p ^ 1][g][kb][lane][0];
#pragma unroll
            for (int hh = 0; hh < 2; hh++)
#pragma unroll
                for (int g = 0; g < MG; g++)
                    acc1[g][hh] = __builtin_amdgcn_mfma_f32_16x16x32_bf16(a1[g], B1[kb][hh], acc1[g][hh], 0, 0, 0);
        }
#pragma unroll
        for (int g = 0; g < MG; g++) {
            float s[4] = {0.f, 0.f, 0.f, 0.f};
#pragma unroll
            for (int hh = 0; hh < 2; hh++)
#pragma unroll
                for (int r = 0; r < 4; r++) {
                    float v = acc1[g][hh][r] + b1v[hh];
                    v = v > 0.f ? v : 0.f;
                    s[r] += v * w2v[hh];
                }
#pragma unroll
            for (int off = 1; off < 16; off <<= 1)
#pragma unroll
                for (int r = 0; r < 4; r++) s[r] += __shfl_xor(s[r], off, 16);
            if (m == 0) {
#pragma unroll
                for (int r = 0; r < 4; r++)
                    pS[p][wave][g * 16 + quad * 4 + r] = s[r];
            }
        }
    }
    __syncthreads();
    if (eM1 >= 0 && wave == 0 && lane < GEDGES) {
        int e = eM1 + lane;
        if (e < E)
            out[e] = pS[p][0][lane] + pS[p][1][lane] +
                     pS[p][2][lane] + pS[p][3][lane] + b2s;
    }
}

// ======================= PATH B: R0 kernel verbatim (2.66 MB ws) =======================
static __device__ __forceinline__ void dma_issue(
        unsigned short* AbufBase, const unsigned short* __restrict__ hb,
        int gOwn, int halfOwn, int lane, int quad, int row) {
#pragma unroll
    for (int kb4 = 0; kb4 < 4; kb4++) {
        const unsigned short* gp = hb + (size_t)row * 128 + kb4 * 32 + quad * 8;
        unsigned short* lp = AbufBase + ((gOwn * 2 + halfOwn) * 4 + kb4) * 512 + lane * 8;
        __builtin_amdgcn_global_load_lds(
            (const __attribute__((address_space(1))) void*)gp,
            (__attribute__((address_space(3))) void*)lp, 16, 0, 0);
    }
}

__global__ __launch_bounds__(256, 3) void k_main_gather(
        const int* __restrict__ src, const int* __restrict__ dst,
        const unsigned short* __restrict__ hb,
        const unsigned short* __restrict__ W0sw, const unsigned short* __restrict__ W1sw,
        const float* __restrict__ b0f, const float* __restrict__ b1f,
        const float* __restrict__ w2f, const float* __restrict__ b2fp,
        float* __restrict__ out, int E, int nGroups) {
    __shared__ __align__(16) unsigned short Abuf[2][MG * 2 * 4 * 64 * 8]; // 2 x 16 KB
    __shared__ __align__(16) unsigned short x1S[2][MG][4][64][8];         // 2 x 8 KB
    __shared__ float pS[2][4][GEDGES];                                    // 1 KB

    const int tid  = threadIdx.x;
    const int wave = tid >> 6;
    const int lane = tid & 63;
    const int quad = lane >> 4;
    const int m    = lane & 15;

    bf16x8 B0[8][2], B1[4][2];
#pragma unroll
    for (int kb = 0; kb < 8; kb++)
#pragma unroll
        for (int hh = 0; hh < 2; hh++)
            B0[kb][hh] = *(const bf16x8*)(W0sw + ((kb * 8 + (wave * 2 + hh)) * 64 + lane) * 8);
#pragma unroll
    for (int kb = 0; kb < 4; kb++)
#pragma unroll
        for (int hh = 0; hh < 2; hh++)
            B1[kb][hh] = *(const bf16x8*)(W1sw + ((kb * 8 + (wave * 2 + hh)) * 64 + lane) * 8);

    float b0v[2], b1v[2], w2v[2];
#pragma unroll
    for (int hh = 0; hh < 2; hh++) {
        int n = (wave * 2 + hh) * 16 + m;
        b0v[hh] = b0f[n];
        b1v[hh] = b1f[n];
        w2v[hh] = w2f[n];
    }
    const float b2s = *b2fp;
    const int stride = gridDim.x;

    const int gOwn = wave >> 1;
    const int halfOwn = wave & 1;
    const int* __restrict__ idxP = halfOwn ? dst : src;

    int gi = blockIdx.x;
    int p = 0;
    int eM1 = -1, eM2 = -1;
    int rN;

    {
        int e = gi * GEDGES + gOwn * 16 + m; if (e >= E) e = E - 1;
        int r0 = idxP[e];
        dma_issue(&Abuf[0][0], hb, gOwn, halfOwn, lane, quad, r0);
        int gN = gi + stride;
        int ebN = (gN < nGroups ? gN : gi) * GEDGES;
        int eN = ebN + gOwn * 16 + m; if (eN >= E) eN = E - 1;
        rN = idxP[eN];
    }

    for (; gi < nGroups; gi += stride, p ^= 1) {
        __syncthreads();

        if (eM2 >= 0 && wave == 0 && lane < GEDGES) {
            int e = eM2 + lane;
            if (e < E)
                out[e] = pS[p ^ 1][0][lane] + pS[p ^ 1][1][lane] +
                         pS[p ^ 1][2][lane] + pS[p ^ 1][3][lane] + b2s;
        }

        if (gi + stride < nGroups)
            dma_issue(&Abuf[p ^ 1][0], hb, gOwn, halfOwn, lane, quad, rN);

        {
            int g2i = gi + 2 * stride;
            int eb2 = (g2i < nGroups ? g2i : gi) * GEDGES;
            int e2 = eb2 + gOwn * 16 + m; if (e2 >= E) e2 = E - 1;
            rN = idxP[e2];
        }

        {
            f32x4 acc0[MG][2];
#pragma unroll
            for (int g = 0; g < MG; g++)
#pragma unroll
                for (int hh = 0; hh < 2; hh++) acc0[g][hh] = (f32x4){0.f, 0.f, 0.f, 0.f};

#pragma unroll
            for (int kb = 0; kb < 8; kb++) {
                bf16x8 a[MG];
#pragma unroll
                for (int g = 0; g < MG; g++)
                    a[g] = *(const bf16x8*)(&Abuf[p][((g * 2 + (kb >> 2)) * 4 + (kb & 3)) * 512 + lane * 8]);
#pragma unroll
                for (int hh = 0; hh < 2; hh++)
#pragma unroll
                    for (int g = 0; g < MG; g++)
                        acc0[g][hh] = __builtin_amdgcn_mfma_f32_16x16x32_bf16(a[g], B0[kb][hh], acc0[g][hh], 0, 0, 0);
            }
#pragma unroll
            for (int g = 0; g < MG; g++) {
#pragma unroll
                for (int hh = 0; hh < 2; hh++) {
                    int qp = (hh << 1) | (m >> 3);
                    int j  = m & 7;
#pragma unroll
                    for (int r = 0; r < 4; r++) {
                        float v = acc0[g][hh][r] + b0v[hh];
                        v = v > 0.f ? v : 0.f;
                        x1S[p][g][wave][qp * 16 + quad * 4 + r][j] = f2bf_hw(v);
                    }
                }
            }
        }

        if (eM1 >= 0) {
            f32x4 acc1[MG][2];
#pragma unroll
            for (int g = 0; g < MG; g++)
#pragma unroll
                for (int hh = 0; hh < 2; hh++) acc1[g][hh] = (f32x4){0.f, 0.f, 0.f, 0.f};

#pragma unroll
            for (int kb = 0; kb < 4; kb++) {
                bf16x8 a1[MG];
#pragma unroll
                for (int g = 0; g < MG; g++)
                    a1[g] = *(const bf16x8*)&x1S[p ^ 1][g][kb][lane][0];
#pragma unroll
                for (int hh = 0; hh < 2; hh++)
#pragma unroll
                    for (int g = 0; g < MG; g++)
                        acc1[g][hh] = __builtin_amdgcn_mfma_f32_16x16x32_bf16(a1[g], B1[kb][hh], acc1[g][hh], 0, 0, 0);
            }
#pragma unroll
            for (int g = 0; g < MG; g++) {
                float s[4] = {0.f, 0.f, 0.f, 0.f};
#pragma unroll
                for (int hh = 0; hh < 2; hh++)
#pragma unroll
                    for (int r = 0; r < 4; r++) {
                        float v = acc1[g][hh][r] + b1v[hh];
                        v = v > 0.f ? v : 0.f;
                        s[r] += v * w2v[hh];
                    }
#pragma unroll
                for (int off = 1; off < 16; off <<= 1)
#pragma unroll
                    for (int r = 0; r < 4; r++) s[r] += __shfl_xor(s[r], off, 16);
                if (m == 0) {
#pragma unroll
                    for (int r = 0; r < 4; r++)
                        pS[p][wave][g * 16 + quad * 4 + r] = s[r];
                }
            }
        }

        eM2 = eM1;
        eM1 = gi * GEDGES;
    }

    __syncthreads();
    if (eM2 >= 0 && wave == 0 && lane < GEDGES) {
        int e = eM2 + lane;
        if (e < E)
            out[e] = pS[p ^ 1][0][lane] + pS[p ^ 1][1][lane] +
                     pS[p ^ 1][2][lane] + pS[p ^ 1][3][lane] + b2s;
    }
    if (eM1 >= 0) {
        f32x4 acc1[MG][2];
#pragma unroll
        for (int g = 0; g < MG; g++)
#pragma unroll
            for (int hh = 0; hh < 2; hh++) acc1[g][hh] = (f32x4){0.f, 0.f, 0.f, 0.f};
#pragma unroll
        for (int kb = 0; kb < 4; kb++) {
            bf16x8 a1[MG];
#pragma unroll
            for (int g = 0; g < MG; g++)
                a1[g] = *(const bf16x8*)&x1S[p ^ 1][g][kb][lane][0];
#pragma unroll
            for (int hh = 0; hh < 2; hh++)
#pragma unroll
                for (int g = 0; g < MG; g++)
                    acc1[g][hh] = __builtin_amdgcn_mfma_f32_16x16x32_bf16(a1[g], B1[kb][hh], acc1[g][hh], 0, 0, 0);
        }
#pragma unroll
        for (int g = 0; g < MG; g++) {
            float s[4] = {0.f, 0.f, 0.f, 0.f};
#pragma unroll
            for (int hh = 0; hh < 2; hh++)
#pragma unroll
                for (int r = 0; r < 4; r++) {
                    float v = acc1[g][hh][r] + b1v[hh];
                    v = v > 0.f ? v : 0.f;
                    s[r] += v * w2v[hh];
                }
#pragma unroll
            for (int off = 1; off < 16; off <<= 1)
#pragma unroll
                for (int r = 0; r < 4; r++) s[r] += __shfl_xor(s[r], off, 16);
            if (m == 0) {
#pragma unroll
                for (int r = 0; r < 4; r++)
                    pS[p][wave][g * 16 + quad * 4 + r] = s[r];
            }
        }
    }
    __syncthreads();
    if (eM1 >= 0 && wave == 0 && lane < GEDGES) {
        int e = eM1 + lane;
        if (e < E)
            out[e] = pS[p][0][lane] + pS[p][1][lane] +
                     pS[p][2][lane] + pS[p][3][lane] + b2s;
    }
}

// ---------------- launcher: pick path by ws_size (launch-invariant host branch) ----------------
extern "C" void kernel_launch(void* const* d_in, const int* in_sizes, int n_in,
                              void* d_out, int out_size, void* d_ws, size_t ws_size,
                              hipStream_t stream) {
    const float* h   = (const float*)d_in[0];
    const int*   src = (const int*)d_in[1];
    const int*   dst = (const int*)d_in[2];
    const float* W0  = (const float*)d_in[3];
    const float* b0  = (const float*)d_in[4];
    const float* W1  = (const float*)d_in[5];
    const float* b1  = (const float*)d_in[6];
    const float* W2  = (const float*)d_in[7];
    const float* b2  = (const float*)d_in[8];
    const float* g0  = (const float*)d_in[9];
    const float* be0 = (const float*)d_in[10];
    const float* g1  = (const float*)d_in[11];
    const float* be1 = (const float*)d_in[12];
    const float* g2  = (const float*)d_in[13];
    const float* be2 = (const float*)d_in[14];
    const float* m0  = (const float*)d_in[15];
    const float* v0  = (const float*)d_in[16];
    const float* m1  = (const float*)d_in[17];
    const float* v1  = (const float*)d_in[18];
    const float* m2  = (const float*)d_in[19];
    const float* v2  = (const float*)d_in[20];
    float* out = (float*)d_out;

    const int hsz = in_sizes[0];          // N*128
    const int E   = in_sizes[1];
    const int N   = hsz / 128;
    const int nGroups = (E + GEDGES - 1) / GEDGES;

    const size_t TAIL = 65536 + 32768 + 512 + 512 + 512 + 16;   // W0sw..b2f
    size_t uvBytes = ((size_t)N * 256 * 2 + 255) & ~(size_t)255;
    size_t needA   = uvBytes + TAIL;

    char* ws = (char*)d_ws;

    if (ws_size >= needA) {
        // ---------- PATH A: factorized (UV f16, 5.22 MB) ----------
        size_t off = uvBytes;
        unsigned short* UV   = (unsigned short*)ws;
        unsigned short* W0sw = (unsigned short*)(ws + off);  off += 65536;
        unsigned short* W1sw = (unsigned short*)(ws + off);  off += 32768;
        float* b0f = (float*)(ws + off);  off += 512;
        float* b1f = (float*)(ws + off);  off += 512;
        float* w2f = (float*)(ws + off);  off += 512;
        float* b2f = (float*)(ws + off);  off += 16;

        k_prep<<<320, 256, 0, stream>>>(h, nullptr, 0, 0,
                                        W0, b0, W1, b1, W2, b2,
                                        g0, be0, m0, v0, g1, be1, m1, v1,
                                        g2, be2, m2, v2,
                                        W0sw, W1sw, b0f, b1f, w2f, b2f);
        int nodeBlocks = (N + 31) / 32;
        k_node<<<nodeBlocks, 256, 0, stream>>>(h, W0sw, b0f, UV, N);
        int nBlocks = nGroups < 768 ? nGroups : 768;
        k_main_uv<<<nBlocks, 256, 0, stream>>>(src, dst, UV, W1sw,
                                               b1f, w2f, b2f, out, E, nGroups);
    } else {
        // ---------- PATH B: R0 verbatim (hb bf16 gather, 2.66 MB) ----------
        size_t off = (size_t)hsz * 2;
        off = (off + 255) & ~(size_t)255;
        unsigned short* hb   = (unsigned short*)ws;
        unsigned short* W0sw = (unsigned short*)(ws + off);  off += 65536;
        unsigned short* W1sw = (unsigned short*)(ws + off);  off += 32768;
        float* b0f = (float*)(ws + off);  off += 512;
        float* b1f = (float*)(ws + off);  off += 512;
        float* w2f = (float*)(ws + off);  off += 512;
        float* b2f = (float*)(ws + off);  off += 16;

        int n4   = hsz / 4;
        int nCvt = (n4 + 255) / 256;
        int prepBlocks = nCvt + 128 + 64 + 128;
        k_prep<<<prepBlocks, 256, 0, stream>>>(h, hb, n4, nCvt,
                                               W0, b0, W1, b1, W2, b2,
                                               g0, be0, m0, v0, g1, be1, m1, v1,
                                               g2, be2, m2, v2,
                                               W0sw, W1sw, b0f, b1f, w2f, b2f);
        int nBlocks = nGroups < 768 ? nGroups : 768;
        k_main_gather<<<nBlocks, 256, 0, stream>>>(src, dst, hb, W0sw, W1sw,
                                                   b0f, b1f, w2f, b2f, out, E, nGroups);
    }
}

// Round 7
// 135.381 us; speedup vs baseline: 1.4481x; 1.0453x over previous
//
#include <hip/hip_runtime.h>
#include <hip/hip_bf16.h>

#define BN_EPS 1e-5f
#define MG 2                 // 16-edge tiles per group
#define GEDGES 32            // edges per group

typedef short bf16x8 __attribute__((ext_vector_type(8)));   // also generic short8
typedef float f32x4  __attribute__((ext_vector_type(4)));

static __device__ __forceinline__ unsigned short f2bf(float f) {
    union { float f; unsigned int u; } v; v.f = f;
    unsigned int u = v.u;
    unsigned int r = (u + 0x7FFFu + ((u >> 16) & 1u)) >> 16;   // RNE
    return (unsigned short)r;
}

static __device__ __forceinline__ unsigned short f2bf_hw(float f) {
    __hip_bfloat16 b = __float2bfloat16(f);
    union { __hip_bfloat16 b; unsigned short u; } v; v.b = b;
    return v.u;
}

static __device__ __forceinline__ unsigned short f2h(float f) {   // f32 -> f16 bits (RNE)
    union { _Float16 h; unsigned short u; } v; v.h = (_Float16)f;
    return v.u;
}

static __device__ __forceinline__ float h2f(short s) {            // f16 bits -> f32
    union { short s; _Float16 h; } v; v.s = s;
    return (float)v.h;
}

// x1S swizzle: byte offset within one phase = g*4096 + kb*1024 + row*16, XOR (kb<<5).
// Write pattern (producer): 8 lanes sharing es hit 4 distinct bank-groups (2-way, free)
// instead of 1 (8-way). Read pattern (lane-contiguous 16B) unchanged modulo a constant
// XOR per (g,kb) -> still conflict-free. Must be applied at ALL read/write sites.
static __device__ __forceinline__ unsigned short* x1_ptr(unsigned short* base, int g, int kb, int row) {
    int off = g * 4096 + (kb * 1024 + (((row * 16)) ^ (kb << 5)));
    return (unsigned short*)((char*)base + off);
}

// ---------------- unified prep kernel (nCvt=0 skips the h->bf16 pass) ----------------
__global__ __launch_bounds__(256) void k_prep(
        const float* __restrict__ h, unsigned short* __restrict__ hb, int n4, int nCvt,
        const float* __restrict__ W0, const float* __restrict__ b0,
        const float* __restrict__ W1, const float* __restrict__ b1,
        const float* __restrict__ W2, const float* __restrict__ b2,
        const float* __restrict__ g0, const float* __restrict__ be0,
        const float* __restrict__ m0, const float* __restrict__ v0,
        const float* __restrict__ g1, const float* __restrict__ be1,
        const float* __restrict__ m1, const float* __restrict__ v1,
        const float* __restrict__ g2, const float* __restrict__ be2,
        const float* __restrict__ m2, const float* __restrict__ v2,
        unsigned short* __restrict__ W0sw, unsigned short* __restrict__ W1sw,
        float* __restrict__ b0f, float* __restrict__ b1f,
        float* __restrict__ w2f, float* __restrict__ b2f) {
    const int b = blockIdx.x;
    const int tid = threadIdx.x;

    if (b < nCvt) {                       // ---- h -> bf16 ----
        int i = b * 256 + tid;
        if (i < n4) {
            float4 f = ((const float4*)h)[i];
            ushort4 o;
            o.x = f2bf(f.x); o.y = f2bf(f.y); o.z = f2bf(f.z); o.w = f2bf(f.w);
            ((ushort4*)hb)[i] = o;
        }
        return;
    }
    int br = b - nCvt;
    if (br < 128) {                        // ---- W0sw (BN0 scale folded) ----
        int t = br * 256 + tid;
        int j = t & 7, lane = (t >> 3) & 63, nt = (t >> 9) & 7, kb = t >> 12;
        int k = kb * 32 + (lane >> 4) * 8 + j;
        int n = nt * 16 + (lane & 15);
        float s = g0[k] * rsqrtf(v0[k] + BN_EPS);
        W0sw[t] = f2bf(W0[n * 256 + k] * s);
        return;
    }
    br -= 128;
    if (br < 64) {                         // ---- W1sw ----
        int t = br * 256 + tid;
        int j = t & 7, lane = (t >> 3) & 63, nt = (t >> 9) & 7, kb = t >> 12;
        int k = kb * 32 + (lane >> 4) * 8 + j;
        int n = nt * 16 + (lane & 15);
        float s = g1[k] * rsqrtf(v1[k] + BN_EPS);
        W1sw[t] = f2bf(W1[n * 128 + k] * s);
        return;
    }
    br -= 64;
    {                                      // ---- folded biases (row = br, 0..127) ----
        if (tid >= 64) return;
        const int i = br, lane = tid;
        float s0 = 0.f;
#pragma unroll
        for (int c = 0; c < 4; c++) {
            int k = c * 64 + lane;
            float sc = g0[k] * rsqrtf(v0[k] + BN_EPS);
            s0 += W0[i * 256 + k] * (be0[k] - m0[k] * sc);
        }
        float s1 = 0.f;
#pragma unroll
        for (int c = 0; c < 2; c++) {
            int k = c * 64 + lane;
            float sc = g1[k] * rsqrtf(v1[k] + BN_EPS);
            s1 += W1[i * 128 + k] * (be1[k] - m1[k] * sc);
        }
        float s2 = 0.f;
        if (i == 0) {
#pragma unroll
            for (int c = 0; c < 2; c++) {
                int k = c * 64 + lane;
                float sc = g2[k] * rsqrtf(v2[k] + BN_EPS);
                s2 += W2[k] * (be2[k] - m2[k] * sc);
            }
        }
#pragma unroll
        for (int off = 1; off < 64; off <<= 1) {
            s0 += __shfl_xor(s0, off);
            s1 += __shfl_xor(s1, off);
            s2 += __shfl_xor(s2, off);
        }
        if (lane == 0) {
            b0f[i] = b0[i] + s0;
            b1f[i] = b1[i] + s1;
            w2f[i] = W2[i] * (g2[i] * rsqrtf(v2[i] + BN_EPS));
            if (i == 0) b2f[0] = b2[0] + s2;
        }
    }
}

// ======================= PATH A: factorized node projection =======================
// UV[n][0..127] = f16(h[n]@W0s^T + b0f); UV[n][128..255] = f16(h[n]@W0d^T).
__global__ __launch_bounds__(256) void k_node(
        const float* __restrict__ h,
        const unsigned short* __restrict__ W0sw,
        const float* __restrict__ b0f,
        unsigned short* __restrict__ UV, int N) {
    const int tid  = threadIdx.x;
    const int wave = tid >> 6;
    const int lane = tid & 63;
    const int quad = lane >> 4;
    const int m    = lane & 15;
    const int nb   = blockIdx.x * 32;

    bf16x8 B0[8][2];
#pragma unroll
    for (int kb = 0; kb < 8; kb++)
#pragma unroll
        for (int hh = 0; hh < 2; hh++)
            B0[kb][hh] = *(const bf16x8*)(W0sw + ((kb * 8 + (wave * 2 + hh)) * 64 + lane) * 8);

    float b0v[2];
#pragma unroll
    for (int hh = 0; hh < 2; hh++) b0v[hh] = b0f[(wave * 2 + hh) * 16 + m];

    f32x4 au[MG][2], av[MG][2];
#pragma unroll
    for (int g = 0; g < MG; g++)
#pragma unroll
        for (int hh = 0; hh < 2; hh++) {
            au[g][hh] = (f32x4){0.f, 0.f, 0.f, 0.f};
            av[g][hh] = (f32x4){0.f, 0.f, 0.f, 0.f};
        }

#pragma unroll
    for (int g = 0; g < MG; g++) {
        int nrow = nb + g * 16 + m; if (nrow >= N) nrow = N - 1;
        const float* hrow = h + (size_t)nrow * 128;
#pragma unroll
        for (int kb = 0; kb < 4; kb++) {
            const float* hp = hrow + kb * 32 + quad * 8;
            f32x4 f0 = *(const f32x4*)hp;
            f32x4 f1 = *(const f32x4*)(hp + 4);
            bf16x8 a;
            a[0] = (short)f2bf_hw(f0[0]); a[1] = (short)f2bf_hw(f0[1]);
            a[2] = (short)f2bf_hw(f0[2]); a[3] = (short)f2bf_hw(f0[3]);
            a[4] = (short)f2bf_hw(f1[0]); a[5] = (short)f2bf_hw(f1[1]);
            a[6] = (short)f2bf_hw(f1[2]); a[7] = (short)f2bf_hw(f1[3]);
#pragma unroll
            for (int hh = 0; hh < 2; hh++) {
                au[g][hh] = __builtin_amdgcn_mfma_f32_16x16x32_bf16(a, B0[kb][hh],     au[g][hh], 0, 0, 0);
                av[g][hh] = __builtin_amdgcn_mfma_f32_16x16x32_bf16(a, B0[kb + 4][hh], av[g][hh], 0, 0, 0);
            }
        }
    }

#pragma unroll
    for (int g = 0; g < MG; g++)
#pragma unroll
        for (int hh = 0; hh < 2; hh++) {
            int col = (wave * 2 + hh) * 16 + m;
#pragma unroll
            for (int r = 0; r < 4; r++) {
                int node = nb + g * 16 + quad * 4 + r;
                if (node < N) {
                    UV[(size_t)node * 256 + col]       = f2h(au[g][hh][r] + b0v[hh]);
                    UV[(size_t)node * 256 + 128 + col] = f2h(av[g][hh][r]);
                }
            }
        }
}

// k_main_uv: R6-verified semantics, restructured pipeline (R6 post-mortem):
//  - idx prefetched 2 groups ahead (rsN in flight), UV issued 1 group ahead using
//    indices already in regs -> no dependent idx->UV stall inside the iteration.
//  - producer at top consumes UV issued mid-previous-iter (distance ~= stage12+barrier).
//  - x1S XOR-swizzled (writes were 8-way bank-conflicted: 4.48M conflict cycles).
//  - 4 blocks/CU (VGPR was 56, LDS 17.4KB) for more latency-hiding TLP.
__global__ __launch_bounds__(256, 4) void k_main_uv(
        const int* __restrict__ src, const int* __restrict__ dst,
        const unsigned short* __restrict__ UV,
        const unsigned short* __restrict__ W1sw,
        const float* __restrict__ b1f, const float* __restrict__ w2f,
        const float* __restrict__ b2fp,
        float* __restrict__ out, int E, int nGroups) {
    __shared__ __align__(16) unsigned short x1S[2][MG][4][64][8];         // 2 x 8 KB
    __shared__ float pS[2][4][GEDGES];                                    // 1 KB

    const int tid  = threadIdx.x;
    const int wave = tid >> 6;
    const int lane = tid & 63;
    const int quad = lane >> 4;
    const int m    = lane & 15;
    const int es   = tid >> 3;   // producer: edge slot 0..31
    const int fc   = tid & 7;    // producer: 16-feature chunk 0..7

    bf16x8 B1[4][2];
#pragma unroll
    for (int kb = 0; kb < 4; kb++)
#pragma unroll
        for (int hh = 0; hh < 2; hh++)
            B1[kb][hh] = *(const bf16x8*)(W1sw + ((kb * 8 + (wave * 2 + hh)) * 64 + lane) * 8);

    float b1v[2], w2v[2];
#pragma unroll
    for (int hh = 0; hh < 2; hh++) {
        int n = (wave * 2 + hh) * 16 + m;
        b1v[hh] = b1f[n];
        w2v[hh] = w2f[n];
    }
    const float b2s = *b2fp;
    const int stride = gridDim.x;

    int gi = blockIdx.x;
    int p = 0;
    int eM1 = -1, eM2 = -1;
    bf16x8 uA, uB, vA, vB;      // UV data for group t (ready at loop top)
    int rsC, rdC;               // indices for group t+1 (resident)
    int rsN, rdN;               // indices for group t+2 (in flight)

    // ---- prologue: UV(t0) + idx(t1) ----
    {
        int e0 = gi * GEDGES + es; if (e0 >= E) e0 = E - 1;
        int rs0 = src[e0], rd0 = dst[e0];
        const bf16x8* up = (const bf16x8*)(UV + (size_t)rs0 * 256 + fc * 16);
        const bf16x8* vp = (const bf16x8*)(UV + (size_t)rd0 * 256 + 128 + fc * 16);
        uA = up[0]; uB = up[1]; vA = vp[0]; vB = vp[1];
        int g1 = gi + stride;
        int e1 = (g1 < nGroups ? g1 : gi) * GEDGES + es; if (e1 >= E) e1 = E - 1;
        rsC = src[e1]; rdC = dst[e1];
    }

    for (; gi < nGroups; gi += stride, p ^= 1) {
        __syncthreads();   // x1S[p^1]/pS[p^1] (written at t-1) visible to all waves

        // ---- producer: x1(G_t) = relu(u + v) -> x1S[p] (swizzled b128 writes) ----
        {
            bf16x8 w0, w1;
#pragma unroll
            for (int j = 0; j < 8; j++) {
                float s0 = h2f(uA[j]) + h2f(vA[j]);
                float s1 = h2f(uB[j]) + h2f(vB[j]);
                s0 = s0 > 0.f ? s0 : 0.f;
                s1 = s1 > 0.f ? s1 : 0.f;
                w0[j] = (short)f2bf_hw(s0);
                w1[j] = (short)f2bf_hw(s1);
            }
            int g = es >> 4, s15 = es & 15, kb = fc >> 1, q0 = (fc & 1) * 2;
            unsigned short* bw = &x1S[p][0][0][0][0];
            *(bf16x8*)x1_ptr(bw, g, kb, q0 * 16 + s15)       = w0;
            *(bf16x8*)x1_ptr(bw, g, kb, (q0 + 1) * 16 + s15) = w1;
        }

        // ---- issue UV(t+1) into the now-dead regs; addresses are resident (rsC/rdC) ----
        {
            const bf16x8* up = (const bf16x8*)(UV + (size_t)rsC * 256 + fc * 16);
            const bf16x8* vp = (const bf16x8*)(UV + (size_t)rdC * 256 + 128 + fc * 16);
            uA = up[0]; uB = up[1]; vA = vp[0]; vB = vp[1];
        }

        // ---- issue idx(t+2) ----
        {
            int gN2 = gi + 2 * stride;
            int e2 = (gN2 < nGroups ? gN2 : gi) * GEDGES + es; if (e2 >= E) e2 = E - 1;
            rsN = src[e2]; rdN = dst[e2];
        }

        // ---- store out(G_{t-2}) from pS[p^1] ----
        if (eM2 >= 0 && wave == 0 && lane < GEDGES) {
            int e = eM2 + lane;
            if (e < E)
                out[e] = pS[p ^ 1][0][lane] + pS[p ^ 1][1][lane] +
                         pS[p ^ 1][2][lane] + pS[p ^ 1][3][lane] + b2s;
        }

        // ---- stage 1+2 (G_{t-1}): x1S[p^1] -> acc1 -> partials -> pS[p] ----
        if (eM1 >= 0) {
            f32x4 acc1[MG][2];
#pragma unroll
            for (int g = 0; g < MG; g++)
#pragma unroll
                for (int hh = 0; hh < 2; hh++) acc1[g][hh] = (f32x4){0.f, 0.f, 0.f, 0.f};

            unsigned short* brd = &x1S[p ^ 1][0][0][0][0];
#pragma unroll
            for (int kb = 0; kb < 4; kb++) {
                bf16x8 a1[MG];
#pragma unroll
                for (int g = 0; g < MG; g++)
                    a1[g] = *(const bf16x8*)x1_ptr(brd, g, kb, lane);
#pragma unroll
                for (int hh = 0; hh < 2; hh++)
#pragma unroll
                    for (int g = 0; g < MG; g++)
                        acc1[g][hh] = __builtin_amdgcn_mfma_f32_16x16x32_bf16(a1[g], B1[kb][hh], acc1[g][hh], 0, 0, 0);
            }

#pragma unroll
            for (int g = 0; g < MG; g++) {
                float s[4] = {0.f, 0.f, 0.f, 0.f};
#pragma unroll
                for (int hh = 0; hh < 2; hh++)
#pragma unroll
                    for (int r = 0; r < 4; r++) {
                        float v = acc1[g][hh][r] + b1v[hh];
                        v = v > 0.f ? v : 0.f;
                        s[r] += v * w2v[hh];
                    }
#pragma unroll
                for (int off = 1; off < 16; off <<= 1)
#pragma unroll
                    for (int r = 0; r < 4; r++) s[r] += __shfl_xor(s[r], off, 16);
                if (m == 0) {
#pragma unroll
                    for (int r = 0; r < 4; r++)
                        pS[p][wave][g * 16 + quad * 4 + r] = s[r];
                }
            }
        }

        eM2 = eM1;
        eM1 = gi * GEDGES;
        rsC = rsN; rdC = rdN;
    }

    // ---- drain: store(G_{L-1}); stage1+2(G_L); store(G_L) ----
    __syncthreads();
    if (eM2 >= 0 && wave == 0 && lane < GEDGES) {
        int e = eM2 + lane;
        if (e < E)
            out[e] = pS[p ^ 1][0][lane] + pS[p ^ 1][1][lane] +
                     pS[p ^ 1][2][lane] + pS[p ^ 1][3][lane] + b2s;
    }
    if (eM1 >= 0) {
        f32x4 acc1[MG][2];
#pragma unroll
        for (int g = 0; g < MG; g++)
#pragma unroll
            for (int hh = 0; hh < 2; hh++) acc1[g][hh] = (f32x4){0.f, 0.f, 0.f, 0.f};
        unsigned short* brd = &x1S[p ^ 1][0][0][0][0];
#pragma unroll
        for (int kb = 0; kb < 4; kb++) {
            bf16x8 a1[MG];
#pragma unroll
            for (int g = 0; g < MG; g++)
                a1[g] = *(const bf16x8*)x1_ptr(brd, g, kb, lane);
#pragma unroll
            for (int hh = 0; hh < 2; hh++)
#pragma unroll
                for (int g = 0; g < MG; g++)
                    acc1[g][hh] = __builtin_amdgcn_mfma_f32_16x16x32_bf16(a1[g], B1[kb][hh], acc1[g][hh], 0, 0, 0);
        }
#pragma unroll
        for (int g = 0; g < MG; g++) {
            float s[4] = {0.f, 0.f, 0.f, 0.f};
#pragma unroll
            for (int hh = 0; hh < 2; hh++)
#pragma unroll
                for (int r = 0; r < 4; r++) {
                    float v = acc1[g][hh][r] + b1v[hh];
                    v = v > 0.f ? v : 0.f;
                    s[r] += v * w2v[hh];
                }
#pragma unroll
            for (int off = 1; off < 16; off <<= 1)
#pragma unroll
                for (int r = 0; r < 4; r++) s[r] += __shfl_xor(s[r], off, 16);
            if (m == 0) {
#pragma unroll
                for (int r = 0; r < 4; r++)
                    pS[p][wave][g * 16 + quad * 4 + r] = s[r];
            }
        }
    }
    __syncthreads();
    if (eM1 >= 0 && wave == 0 && lane < GEDGES) {
        int e = eM1 + lane;
        if (e < E)
            out[e] = pS[p][0][lane] + pS[p][1][lane] +
                     pS[p][2][lane] + pS[p][3][lane] + b2s;
    }
}

// ======================= PATH B: R0 kernel verbatim (2.66 MB ws) =======================
static __device__ __forceinline__ void dma_issue(
        unsigned short* AbufBase, const unsigned short* __restrict__ hb,
        int gOwn, int halfOwn, int lane, int quad, int row) {
#pragma unroll
    for (int kb4 = 0; kb4 < 4; kb4++) {
        const unsigned short* gp = hb + (size_t)row * 128 + kb4 * 32 + quad * 8;
        unsigned short* lp = AbufBase + ((gOwn * 2 + halfOwn) * 4 + kb4) * 512 + lane * 8;
        __builtin_amdgcn_global_load_lds(
            (const __attribute__((address_space(1))) void*)gp,
            (__attribute__((address_space(3))) void*)lp, 16, 0, 0);
    }
}

__global__ __launch_bounds__(256, 3) void k_main_gather(
        const int* __restrict__ src, const int* __restrict__ dst,
        const unsigned short* __restrict__ hb,
        const unsigned short* __restrict__ W0sw, const unsigned short* __restrict__ W1sw,
        const float* __restrict__ b0f, const float* __restrict__ b1f,
        const float* __restrict__ w2f, const float* __restrict__ b2fp,
        float* __restrict__ out, int E, int nGroups) {
    __shared__ __align__(16) unsigned short Abuf[2][MG * 2 * 4 * 64 * 8]; // 2 x 16 KB
    __shared__ __align__(16) unsigned short x1S[2][MG][4][64][8];         // 2 x 8 KB
    __shared__ float pS[2][4][GEDGES];                                    // 1 KB

    const int tid  = threadIdx.x;
    const int wave = tid >> 6;
    const int lane = tid & 63;
    const int quad = lane >> 4;
    const int m    = lane & 15;

    bf16x8 B0[8][2], B1[4][2];
#pragma unroll
    for (int kb = 0; kb < 8; kb++)
#pragma unroll
        for (int hh = 0; hh < 2; hh++)
            B0[kb][hh] = *(const bf16x8*)(W0sw + ((kb * 8 + (wave * 2 + hh)) * 64 + lane) * 8);
#pragma unroll
    for (int kb = 0; kb < 4; kb++)
#pragma unroll
        for (int hh = 0; hh < 2; hh++)
            B1[kb][hh] = *(const bf16x8*)(W1sw + ((kb * 8 + (wave * 2 + hh)) * 64 + lane) * 8);

    float b0v[2], b1v[2], w2v[2];
#pragma unroll
    for (int hh = 0; hh < 2; hh++) {
        int n = (wave * 2 + hh) * 16 + m;
        b0v[hh] = b0f[n];
        b1v[hh] = b1f[n];
        w2v[hh] = w2f[n];
    }
    const float b2s = *b2fp;
    const int stride = gridDim.x;

    const int gOwn = wave >> 1;
    const int halfOwn = wave & 1;
    const int* __restrict__ idxP = halfOwn ? dst : src;

    int gi = blockIdx.x;
    int p = 0;
    int eM1 = -1, eM2 = -1;
    int rN;

    {
        int e = gi * GEDGES + gOwn * 16 + m; if (e >= E) e = E - 1;
        int r0 = idxP[e];
        dma_issue(&Abuf[0][0], hb, gOwn, halfOwn, lane, quad, r0);
        int gN = gi + stride;
        int ebN = (gN < nGroups ? gN : gi) * GEDGES;
        int eN = ebN + gOwn * 16 + m; if (eN >= E) eN = E - 1;
        rN = idxP[eN];
    }

    for (; gi < nGroups; gi += stride, p ^= 1) {
        __syncthreads();

        if (eM2 >= 0 && wave == 0 && lane < GEDGES) {
            int e = eM2 + lane;
            if (e < E)
                out[e] = pS[p ^ 1][0][lane] + pS[p ^ 1][1][lane] +
                         pS[p ^ 1][2][lane] + pS[p ^ 1][3][lane] + b2s;
        }

        if (gi + stride < nGroups)
            dma_issue(&Abuf[p ^ 1][0], hb, gOwn, halfOwn, lane, quad, rN);

        {
            int g2i = gi + 2 * stride;
            int eb2 = (g2i < nGroups ? g2i : gi) * GEDGES;
            int e2 = eb2 + gOwn * 16 + m; if (e2 >= E) e2 = E - 1;
            rN = idxP[e2];
        }

        {
            f32x4 acc0[MG][2];
#pragma unroll
            for (int g = 0; g < MG; g++)
#pragma unroll
                for (int hh = 0; hh < 2; hh++) acc0[g][hh] = (f32x4){0.f, 0.f, 0.f, 0.f};

#pragma unroll
            for (int kb = 0; kb < 8; kb++) {
                bf16x8 a[MG];
#pragma unroll
                for (int g = 0; g < MG; g++)
                    a[g] = *(const bf16x8*)(&Abuf[p][((g * 2 + (kb >> 2)) * 4 + (kb & 3)) * 512 + lane * 8]);
#pragma unroll
                for (int hh = 0; hh < 2; hh++)
#pragma unroll
                    for (int g = 0; g < MG; g++)
                        acc0[g][hh] = __builtin_amdgcn_mfma_f32_16x16x32_bf16(a[g], B0[kb][hh], acc0[g][hh], 0, 0, 0);
            }
#pragma unroll
            for (int g = 0; g < MG; g++) {
#pragma unroll
                for (int hh = 0; hh < 2; hh++) {
                    int qp = (hh << 1) | (m >> 3);
                    int j  = m & 7;
#pragma unroll
                    for (int r = 0; r < 4; r++) {
                        float v = acc0[g][hh][r] + b0v[hh];
                        v = v > 0.f ? v : 0.f;
                        x1S[p][g][wave][qp * 16 + quad * 4 + r][j] = f2bf_hw(v);
                    }
                }
            }
        }

        if (eM1 >= 0) {
            f32x4 acc1[MG][2];
#pragma unroll
            for (int g = 0; g < MG; g++)
#pragma unroll
                for (int hh = 0; hh < 2; hh++) acc1[g][hh] = (f32x4){0.f, 0.f, 0.f, 0.f};

#pragma unroll
            for (int kb = 0; kb < 4; kb++) {
                bf16x8 a1[MG];
#pragma unroll
                for (int g = 0; g < MG; g++)
                    a1[g] = *(const bf16x8*)&x1S[p ^ 1][g][kb][lane][0];
#pragma unroll
                for (int hh = 0; hh < 2; hh++)
#pragma unroll
                    for (int g = 0; g < MG; g++)
                        acc1[g][hh] = __builtin_amdgcn_mfma_f32_16x16x32_bf16(a1[g], B1[kb][hh], acc1[g][hh], 0, 0, 0);
            }
#pragma unroll
            for (int g = 0; g < MG; g++) {
                float s[4] = {0.f, 0.f, 0.f, 0.f};
#pragma unroll
                for (int hh = 0; hh < 2; hh++)
#pragma unroll
                    for (int r = 0; r < 4; r++) {
                        float v = acc1[g][hh][r] + b1v[hh];
                        v = v > 0.f ? v : 0.f;
                        s[r] += v * w2v[hh];
                    }
#pragma unroll
                for (int off = 1; off < 16; off <<= 1)
#pragma unroll
                    for (int r = 0; r < 4; r++) s[r] += __shfl_xor(s[r], off, 16);
                if (m == 0) {
#pragma unroll
                    for (int r = 0; r < 4; r++)
                        pS[p][wave][g * 16 + quad * 4 + r] = s[r];
                }
            }
        }

        eM2 = eM1;
        eM1 = gi * GEDGES;
    }

    __syncthreads();
    if (eM2 >= 0 && wave == 0 && lane < GEDGES) {
        int e = eM2 + lane;
        if (e < E)
            out[e] = pS[p ^ 1][0][lane] + pS[p ^ 1][1][lane] +
                     pS[p ^ 1][2][lane] + pS[p ^ 1][3][lane] + b2s;
    }
    if (eM1 >= 0) {
        f32x4 acc1[MG][2];
#pragma unroll
        for (int g = 0; g < MG; g++)
#pragma unroll
            for (int hh = 0; hh < 2; hh++) acc1[g][hh] = (f32x4){0.f, 0.f, 0.f, 0.f};
#pragma unroll
        for (int kb = 0; kb < 4; kb++) {
            bf16x8 a1[MG];
#pragma unroll
            for (int g = 0; g < MG; g++)
                a1[g] = *(const bf16x8*)&x1S[p ^ 1][g][kb][lane][0];
#pragma unroll
            for (int hh = 0; hh < 2; hh++)
#pragma unroll
                for (int g = 0; g < MG; g++)
                    acc1[g][hh] = __builtin_amdgcn_mfma_f32_16x16x32_bf16(a1[g], B1[kb][hh], acc1[g][hh], 0, 0, 0);
        }
#pragma unroll
        for (int g = 0; g < MG; g++) {
            float s[4] = {0.f, 0.f, 0.f, 0.f};
#pragma unroll
            for (int hh = 0; hh < 2; hh++)
#pragma unroll
                for (int r = 0; r < 4; r++) {
                    float v = acc1[g][hh][r] + b1v[hh];
                    v = v > 0.f ? v : 0.f;
                    s[r] += v * w2v[hh];
                }
#pragma unroll
            for (int off = 1; off < 16; off <<= 1)
#pragma unroll
                for (int r = 0; r < 4; r++) s[r] += __shfl_xor(s[r], off, 16);
            if (m == 0) {
#pragma unroll
                for (int r = 0; r < 4; r++)
                    pS[p][wave][g * 16 + quad * 4 + r] = s[r];
            }
        }
    }
    __syncthreads();
    if (eM1 >= 0 && wave == 0 && lane < GEDGES) {
        int e = eM1 + lane;
        if (e < E)
            out[e] = pS[p][0][lane] + pS[p][1][lane] +
                     pS[p][2][lane] + pS[p][3][lane] + b2s;
    }
}

// ---------------- launcher: pick path by ws_size (launch-invariant host branch) ----------------
extern "C" void kernel_launch(void* const* d_in, const int* in_sizes, int n_in,
                              void* d_out, int out_size, void* d_ws, size_t ws_size,
                              hipStream_t stream) {
    const float* h   = (const float*)d_in[0];
    const int*   src = (const int*)d_in[1];
    const int*   dst = (const int*)d_in[2];
    const float* W0  = (const float*)d_in[3];
    const float* b0  = (const float*)d_in[4];
    const float* W1  = (const float*)d_in[5];
    const float* b1  = (const float*)d_in[6];
    const float* W2  = (const float*)d_in[7];
    const float* b2  = (const float*)d_in[8];
    const float* g0  = (const float*)d_in[9];
    const float* be0 = (const float*)d_in[10];
    const float* g1  = (const float*)d_in[11];
    const float* be1 = (const float*)d_in[12];
    const float* g2  = (const float*)d_in[13];
    const float* be2 = (const float*)d_in[14];
    const float* m0  = (const float*)d_in[15];
    const float* v0  = (const float*)d_in[16];
    const float* m1  = (const float*)d_in[17];
    const float* v1  = (const float*)d_in[18];
    const float* m2  = (const float*)d_in[19];
    const float* v2  = (const float*)d_in[20];
    float* out = (float*)d_out;

    const int hsz = in_sizes[0];          // N*128
    const int E   = in_sizes[1];
    const int N   = hsz / 128;
    const int nGroups = (E + GEDGES - 1) / GEDGES;

    const size_t TAIL = 65536 + 32768 + 512 + 512 + 512 + 16;   // W0sw..b2f
    size_t uvBytes = ((size_t)N * 256 * 2 + 255) & ~(size_t)255;
    size_t needA   = uvBytes + TAIL;

    char* ws = (char*)d_ws;

    if (ws_size >= needA) {
        // ---------- PATH A: factorized (UV f16, 5.22 MB) ----------
        size_t off = uvBytes;
        unsigned short* UV   = (unsigned short*)ws;
        unsigned short* W0sw = (unsigned short*)(ws + off);  off += 65536;
        unsigned short* W1sw = (unsigned short*)(ws + off);  off += 32768;
        float* b0f = (float*)(ws + off);  off += 512;
        float* b1f = (float*)(ws + off);  off += 512;
        float* w2f = (float*)(ws + off);  off += 512;
        float* b2f = (float*)(ws + off);  off += 16;

        k_prep<<<320, 256, 0, stream>>>(h, nullptr, 0, 0,
                                        W0, b0, W1, b1, W2, b2,
                                        g0, be0, m0, v0, g1, be1, m1, v1,
                                        g2, be2, m2, v2,
                                        W0sw, W1sw, b0f, b1f, w2f, b2f);
        int nodeBlocks = (N + 31) / 32;
        k_node<<<nodeBlocks, 256, 0, stream>>>(h, W0sw, b0f, UV, N);
        int nBlocks = nGroups < 1024 ? nGroups : 1024;   // 4 blocks/CU
        k_main_uv<<<nBlocks, 256, 0, stream>>>(src, dst, UV, W1sw,
                                               b1f, w2f, b2f, out, E, nGroups);
    } else {
        // ---------- PATH B: R0 verbatim (hb bf16 gather, 2.66 MB) ----------
        size_t off = (size_t)hsz * 2;
        off = (off + 255) & ~(size_t)255;
        unsigned short* hb   = (unsigned short*)ws;
        unsigned short* W0sw = (unsigned short*)(ws + off);  off += 65536;
        unsigned short* W1sw = (unsigned short*)(ws + off);  off += 32768;
        float* b0f = (float*)(ws + off);  off += 512;
        float* b1f = (float*)(ws + off);  off += 512;
        float* w2f = (float*)(ws + off);  off += 512;
        float* b2f = (float*)(ws + off);  off += 16;

        int n4   = hsz / 4;
        int nCvt = (n4 + 255) / 256;
        int prepBlocks = nCvt + 128 + 64 + 128;
        k_prep<<<prepBlocks, 256, 0, stream>>>(h, hb, n4, nCvt,
                                               W0, b0, W1, b1, W2, b2,
                                               g0, be0, m0, v0, g1, be1, m1, v1,
                                               g2, be2, m2, v2,
                                               W0sw, W1sw, b0f, b1f, w2f, b2f);
        int nBlocks = nGroups < 768 ? nGroups : 768;
        k_main_gather<<<nBlocks, 256, 0, stream>>>(src, dst, hb, W0sw, W1sw,
                                                   b0f, b1f, w2f, b2f, out, E, nGroups);
    }
}

// Round 8
// 134.845 us; speedup vs baseline: 1.4538x; 1.0040x over previous
//
#include <hip/hip_runtime.h>
#include <hip/hip_bf16.h>

#define BN_EPS 1e-5f
#define MG 2                 // 16-node tiles per k_node block

typedef short bf16x8 __attribute__((ext_vector_type(8)));   // also generic short8
typedef float f32x4  __attribute__((ext_vector_type(4)));

static __device__ __forceinline__ unsigned short f2bf(float f) {
    union { float f; unsigned int u; } v; v.f = f;
    unsigned int u = v.u;
    unsigned int r = (u + 0x7FFFu + ((u >> 16) & 1u)) >> 16;   // RNE
    return (unsigned short)r;
}

static __device__ __forceinline__ unsigned short f2bf_hw(float f) {
    __hip_bfloat16 b = __float2bfloat16(f);
    union { __hip_bfloat16 b; unsigned short u; } v; v.b = b;
    return v.u;
}

static __device__ __forceinline__ unsigned short f2h(float f) {   // f32 -> f16 bits (RNE)
    union { _Float16 h; unsigned short u; } v; v.h = (_Float16)f;
    return v.u;
}

static __device__ __forceinline__ float h2f(short s) {            // f16 bits -> f32
    union { short s; _Float16 h; } v; v.s = s;
    return (float)v.h;
}

// ---------------- prep kernel: weights only ----------------
__global__ __launch_bounds__(256) void k_prep(
        const float* __restrict__ W0, const float* __restrict__ b0,
        const float* __restrict__ W1, const float* __restrict__ b1,
        const float* __restrict__ W2, const float* __restrict__ b2,
        const float* __restrict__ g0, const float* __restrict__ be0,
        const float* __restrict__ m0, const float* __restrict__ v0,
        const float* __restrict__ g1, const float* __restrict__ be1,
        const float* __restrict__ m1, const float* __restrict__ v1,
        const float* __restrict__ g2, const float* __restrict__ be2,
        const float* __restrict__ m2, const float* __restrict__ v2,
        unsigned short* __restrict__ W0sw, unsigned short* __restrict__ W1sw,
        float* __restrict__ b0f, float* __restrict__ b1f,
        float* __restrict__ w2f, float* __restrict__ b2f) {
    int br = blockIdx.x;
    const int tid = threadIdx.x;

    if (br < 128) {                        // ---- W0sw (BN0 scale folded) ----
        int t = br * 256 + tid;
        int j = t & 7, lane = (t >> 3) & 63, nt = (t >> 9) & 7, kb = t >> 12;
        int k = kb * 32 + (lane >> 4) * 8 + j;
        int n = nt * 16 + (lane & 15);
        float s = g0[k] * rsqrtf(v0[k] + BN_EPS);
        W0sw[t] = f2bf(W0[n * 256 + k] * s);
        return;
    }
    br -= 128;
    if (br < 64) {                         // ---- W1sw ----
        int t = br * 256 + tid;
        int j = t & 7, lane = (t >> 3) & 63, nt = (t >> 9) & 7, kb = t >> 12;
        int k = kb * 32 + (lane >> 4) * 8 + j;
        int n = nt * 16 + (lane & 15);
        float s = g1[k] * rsqrtf(v1[k] + BN_EPS);
        W1sw[t] = f2bf(W1[n * 128 + k] * s);
        return;
    }
    br -= 64;
    {                                      // ---- folded biases (row = br, 0..127) ----
        if (tid >= 64) return;
        const int i = br, lane = tid;
        float s0 = 0.f;
#pragma unroll
        for (int c = 0; c < 4; c++) {
            int k = c * 64 + lane;
            float sc = g0[k] * rsqrtf(v0[k] + BN_EPS);
            s0 += W0[i * 256 + k] * (be0[k] - m0[k] * sc);
        }
        float s1 = 0.f;
#pragma unroll
        for (int c = 0; c < 2; c++) {
            int k = c * 64 + lane;
            float sc = g1[k] * rsqrtf(v1[k] + BN_EPS);
            s1 += W1[i * 128 + k] * (be1[k] - m1[k] * sc);
        }
        float s2 = 0.f;
        if (i == 0) {
#pragma unroll
            for (int c = 0; c < 2; c++) {
                int k = c * 64 + lane;
                float sc = g2[k] * rsqrtf(v2[k] + BN_EPS);
                s2 += W2[k] * (be2[k] - m2[k] * sc);
            }
        }
#pragma unroll
        for (int off = 1; off < 64; off <<= 1) {
            s0 += __shfl_xor(s0, off);
            s1 += __shfl_xor(s1, off);
            s2 += __shfl_xor(s2, off);
        }
        if (lane == 0) {
            b0f[i] = b0[i] + s0;
            b1f[i] = b1[i] + s1;
            w2f[i] = W2[i] * (g2[i] * rsqrtf(v2[i] + BN_EPS));
            if (i == 0) b2f[0] = b2[0] + s2;
        }
    }
}

// ---------------- node projection: UV[n][0..127]=f16(h@W0s^T+b0f), [128..255]=f16(h@W0d^T) ----
__global__ __launch_bounds__(256) void k_node(
        const float* __restrict__ h,
        const unsigned short* __restrict__ W0sw,
        const float* __restrict__ b0f,
        unsigned short* __restrict__ UV, int N) {
    const int tid  = threadIdx.x;
    const int wave = tid >> 6;
    const int lane = tid & 63;
    const int quad = lane >> 4;
    const int m    = lane & 15;
    const int nb   = blockIdx.x * 32;

    bf16x8 B0[8][2];
#pragma unroll
    for (int kb = 0; kb < 8; kb++)
#pragma unroll
        for (int hh = 0; hh < 2; hh++)
            B0[kb][hh] = *(const bf16x8*)(W0sw + ((kb * 8 + (wave * 2 + hh)) * 64 + lane) * 8);

    float b0v[2];
#pragma unroll
    for (int hh = 0; hh < 2; hh++) b0v[hh] = b0f[(wave * 2 + hh) * 16 + m];

    f32x4 au[MG][2], av[MG][2];
#pragma unroll
    for (int g = 0; g < MG; g++)
#pragma unroll
        for (int hh = 0; hh < 2; hh++) {
            au[g][hh] = (f32x4){0.f, 0.f, 0.f, 0.f};
            av[g][hh] = (f32x4){0.f, 0.f, 0.f, 0.f};
        }

#pragma unroll
    for (int g = 0; g < MG; g++) {
        int nrow = nb + g * 16 + m; if (nrow >= N) nrow = N - 1;
        const float* hrow = h + (size_t)nrow * 128;
#pragma unroll
        for (int kb = 0; kb < 4; kb++) {
            const float* hp = hrow + kb * 32 + quad * 8;
            f32x4 f0 = *(const f32x4*)hp;
            f32x4 f1 = *(const f32x4*)(hp + 4);
            bf16x8 a;
            a[0] = (short)f2bf_hw(f0[0]); a[1] = (short)f2bf_hw(f0[1]);
            a[2] = (short)f2bf_hw(f0[2]); a[3] = (short)f2bf_hw(f0[3]);
            a[4] = (short)f2bf_hw(f1[0]); a[5] = (short)f2bf_hw(f1[1]);
            a[6] = (short)f2bf_hw(f1[2]); a[7] = (short)f2bf_hw(f1[3]);
#pragma unroll
            for (int hh = 0; hh < 2; hh++) {
                au[g][hh] = __builtin_amdgcn_mfma_f32_16x16x32_bf16(a, B0[kb][hh],     au[g][hh], 0, 0, 0);
                av[g][hh] = __builtin_amdgcn_mfma_f32_16x16x32_bf16(a, B0[kb + 4][hh], av[g][hh], 0, 0, 0);
            }
        }
    }

#pragma unroll
    for (int g = 0; g < MG; g++)
#pragma unroll
        for (int hh = 0; hh < 2; hh++) {
            int col = (wave * 2 + hh) * 16 + m;
#pragma unroll
            for (int r = 0; r < 4; r++) {
                int node = nb + g * 16 + quad * 4 + r;
                if (node < N) {
                    UV[(size_t)node * 256 + col]       = f2h(au[g][hh][r] + b0v[hh]);
                    UV[(size_t)node * 256 + 128 + col] = f2h(av[g][hh][r]);
                }
            }
        }
}

// ---------------- edge kernel: barrier-free, wave-independent ----------------
// R7 post-mortem: the old producer/consumer x1S handoff forced __syncthreads each iter,
// whose implicit s_waitcnt vmcnt(0) drained the UV prefetch -> every iteration's barrier
// waited on the slowest L3/HBM gather (~2200 cy/block-iter vs ~500 of work). Fix: each
// wave owns 16 edges end-to-end. The MFMA A-frag (lane l <- edge l&15, k=kb*32+(l>>4)*8+j)
// is directly per-lane gatherable from UV: 16B u-chunk + 16B v-chunk per kb, f32 add ->
// relu -> bf16 in-register (numerics identical to the R6/R7-verified path). B1 held
// full-width per wave (8nt x 4kb = 128 VGPR). ZERO LDS, ZERO barriers -> gather misses
// overlap across 8 independent waves/CU. ~240 VGPR -> (256,2), grid 512 exact-resident.
// Spill tripwire: WRITE_SIZE should stay ~1250 KB; VGPR_Count ~240-256.
__global__ __launch_bounds__(256, 2) void k_edge(
        const int* __restrict__ src, const int* __restrict__ dst,
        const unsigned short* __restrict__ UV,
        const unsigned short* __restrict__ W1sw,
        const float* __restrict__ b1f, const float* __restrict__ w2f,
        const float* __restrict__ b2fp,
        float* __restrict__ out, int E, int nG) {
    const int tid  = threadIdx.x;
    const int wave = tid >> 6;
    const int lane = tid & 63;
    const int q    = lane >> 4;
    const int m    = lane & 15;

    // full stage-1 weights per wave: nt 0..7, kb 0..3 (128 VGPR)
    bf16x8 B1f[8][4];
#pragma unroll
    for (int nt = 0; nt < 8; nt++)
#pragma unroll
        for (int kb = 0; kb < 4; kb++)
            B1f[nt][kb] = *(const bf16x8*)(W1sw + ((kb * 8 + nt) * 64 + lane) * 8);

    float b1v[8], w2v[8];
#pragma unroll
    for (int nt = 0; nt < 8; nt++) {
        b1v[nt] = b1f[nt * 16 + m];
        w2v[nt] = w2f[nt * 16 + m];
    }
    const float b2s = *b2fp;
    const int stride = gridDim.x;

    int gi = blockIdx.x;
    bf16x8 uF[4], vF[4];        // raw f16 UV chunks for group t (this lane's A-frag data)
    int rsC, rdC;               // node indices for group t+1 (resident)

    // ---- prologue: idx(t0) -> UV(t0) issue; idx(t1) ----
    {
        int e0 = gi * 64 + wave * 16 + m; if (e0 >= E) e0 = E - 1;
        int rs0 = src[e0], rd0 = dst[e0];
#pragma unroll
        for (int kb = 0; kb < 4; kb++) {
            uF[kb] = *(const bf16x8*)(UV + (size_t)rs0 * 256 + kb * 32 + q * 8);
            vF[kb] = *(const bf16x8*)(UV + (size_t)rd0 * 256 + 128 + kb * 32 + q * 8);
        }
        int g1 = gi + stride;
        int e1 = (g1 < nG ? g1 : gi) * 64 + wave * 16 + m; if (e1 >= E) e1 = E - 1;
        rsC = src[e1]; rdC = dst[e1];
    }

    for (; gi < nG; gi += stride) {
        // ---- build A-frags: a[kb][j] = bf16(relu(f32(u)+f32(v))) ----
        bf16x8 a[4];
#pragma unroll
        for (int kb = 0; kb < 4; kb++)
#pragma unroll
            for (int j = 0; j < 8; j++) {
                float s = h2f(uF[kb][j]) + h2f(vF[kb][j]);
                s = s > 0.f ? s : 0.f;
                a[kb][j] = (short)f2bf_hw(s);
            }

        // ---- issue UV(t+1) into now-dead uF/vF (indices resident); covered by MFMA+stage2 ----
        {
            int rs_ = rsC, rd_ = rdC;
#pragma unroll
            for (int kb = 0; kb < 4; kb++) {
                uF[kb] = *(const bf16x8*)(UV + (size_t)rs_ * 256 + kb * 32 + q * 8);
                vF[kb] = *(const bf16x8*)(UV + (size_t)rd_ * 256 + 128 + kb * 32 + q * 8);
            }
        }
        // ---- issue idx(t+2) ----
        {
            int g2 = gi + 2 * stride;
            int e2 = (g2 < nG ? g2 : gi) * 64 + wave * 16 + m; if (e2 >= E) e2 = E - 1;
            rsC = src[e2]; rdC = dst[e2];
        }

        // ---- stage 1: 32 MFMA (8 independent acc chains) ----
        f32x4 acc[8];
#pragma unroll
        for (int nt = 0; nt < 8; nt++) acc[nt] = (f32x4){0.f, 0.f, 0.f, 0.f};
#pragma unroll
        for (int kb = 0; kb < 4; kb++)
#pragma unroll
            for (int nt = 0; nt < 8; nt++)
                acc[nt] = __builtin_amdgcn_mfma_f32_16x16x32_bf16(a[kb], B1f[nt][kb], acc[nt], 0, 0, 0);

        // ---- stage 2: relu(x2 + b1) . w2, reduce over the 16 feature-lanes ----
        float s[4] = {0.f, 0.f, 0.f, 0.f};
#pragma unroll
        for (int nt = 0; nt < 8; nt++)
#pragma unroll
            for (int r = 0; r < 4; r++) {
                float v = acc[nt][r] + b1v[nt];
                v = v > 0.f ? v : 0.f;
                s[r] += v * w2v[nt];
            }
#pragma unroll
        for (int off = 1; off < 16; off <<= 1)
#pragma unroll
            for (int r = 0; r < 4; r++) s[r] += __shfl_xor(s[r], off, 16);

        if (m == 0) {
            int eB = gi * 64 + wave * 16 + q * 4;
#pragma unroll
            for (int r = 0; r < 4; r++) {
                int e = eB + r;
                if (e < E) out[e] = s[r] + b2s;
            }
        }
    }
}

// ---------------- launcher ----------------
extern "C" void kernel_launch(void* const* d_in, const int* in_sizes, int n_in,
                              void* d_out, int out_size, void* d_ws, size_t ws_size,
                              hipStream_t stream) {
    const float* h   = (const float*)d_in[0];
    const int*   src = (const int*)d_in[1];
    const int*   dst = (const int*)d_in[2];
    const float* W0  = (const float*)d_in[3];
    const float* b0  = (const float*)d_in[4];
    const float* W1  = (const float*)d_in[5];
    const float* b1  = (const float*)d_in[6];
    const float* W2  = (const float*)d_in[7];
    const float* b2  = (const float*)d_in[8];
    const float* g0  = (const float*)d_in[9];
    const float* be0 = (const float*)d_in[10];
    const float* g1  = (const float*)d_in[11];
    const float* be1 = (const float*)d_in[12];
    const float* g2  = (const float*)d_in[13];
    const float* be2 = (const float*)d_in[14];
    const float* m0  = (const float*)d_in[15];
    const float* v0  = (const float*)d_in[16];
    const float* m1  = (const float*)d_in[17];
    const float* v1  = (const float*)d_in[18];
    const float* m2  = (const float*)d_in[19];
    const float* v2  = (const float*)d_in[20];
    float* out = (float*)d_out;

    const int hsz = in_sizes[0];          // N*128
    const int E   = in_sizes[1];
    const int N   = hsz / 128;

    // ws layout (verified in R6/R7): UV f16 (N*256) + weight tail; ~5.22 MB total
    char* ws = (char*)d_ws;
    unsigned short* UV = (unsigned short*)ws;
    size_t off = ((size_t)N * 256 * 2 + 255) & ~(size_t)255;
    unsigned short* W0sw = (unsigned short*)(ws + off);  off += 65536;
    unsigned short* W1sw = (unsigned short*)(ws + off);  off += 32768;
    float* b0f = (float*)(ws + off);  off += 512;
    float* b1f = (float*)(ws + off);  off += 512;
    float* w2f = (float*)(ws + off);  off += 512;
    float* b2f = (float*)(ws + off);  off += 16;

    k_prep<<<320, 256, 0, stream>>>(W0, b0, W1, b1, W2, b2,
                                    g0, be0, m0, v0, g1, be1, m1, v1,
                                    g2, be2, m2, v2,
                                    W0sw, W1sw, b0f, b1f, w2f, b2f);

    int nodeBlocks = (N + 31) / 32;
    k_node<<<nodeBlocks, 256, 0, stream>>>(h, W0sw, b0f, UV, N);

    int nG = (E + 63) / 64;                 // 64 edges per block (4 waves x 16)
    int nBlocks = nG < 512 ? nG : 512;      // 2 blocks/CU exact-resident (0 LDS, ~240 VGPR)
    k_edge<<<nBlocks, 256, 0, stream>>>(src, dst, UV, W1sw,
                                        b1f, w2f, b2f, out, E, nG);
}